// Round 1
// baseline (195.050 us; speedup 1.0000x reference)
//
#include <hip/hip_runtime.h>
#include <math.h>

#define DIM 192
#define HW 56
#define NPIX 3136        // 56*56
#define NSAMP 16
#define KL 21
#define KS 5
#define PADL 10
#define TROWS 76         // 56 + 2*10
#define TCOLS 80         // padded row stride (floats), 16B-aligned rows
#define GN_EPS 1e-5f

typedef float f32x4 __attribute__((ext_vector_type(4)));
typedef __bf16 bf16x8 __attribute__((ext_vector_type(8)));

// ---------------- ws layout (bytes) ----------------
// tmp      : 9,633,792 f32  @ 0            (38,535,168 B)
// partials : 3072*2 f32     @ 38,535,168   (24,576 B)
// stats    : 32 f32         @ 38,559,744   (128 B)
// wb       : 36,864 bf16    @ 38,559,872   (73,728 B)
#define WS_OFF_PARTIALS 38535168
#define WS_OFF_STATS    38559744
#define WS_OFF_WB       38559872

// -------- Kernel P: cast pointwise weights to bf16 --------
__global__ void conv_w_kernel(const float* __restrict__ w, __bf16* __restrict__ wb) {
    int i = blockIdx.x * 256 + threadIdx.x;
    if (i < DIM * DIM) wb[i] = (__bf16)w[i];
}

// -------- Kernel A: fused depthwise 21x21 + 5x5 conv, per-(n,c) plane --------
__global__ __launch_bounds__(256)
void dwconv_kernel(const float* __restrict__ x,
                   const float* __restrict__ wl,
                   const float* __restrict__ wsm,
                   float* __restrict__ tmp,
                   float* __restrict__ partials) {
    __shared__ float tile[TROWS * TCOLS];   // 24,320 B
    __shared__ float wrow[21 * 24];         // 21x21 padded to 24 cols
    __shared__ float wsrow[5 * 8];          // 5x5 padded to 8 cols
    __shared__ float red[8];

    const int bid = blockIdx.x;             // n*DIM + c
    const int c = bid % DIM;
    const int tid = threadIdx.x;

    const float* xp = x + (size_t)bid * NPIX;

    for (int i = tid; i < 21 * 24; i += 256) {
        int r = i / 24, cc = i % 24;
        wrow[i] = (cc < 21) ? wl[c * 441 + r * 21 + cc] : 0.f;
    }
    for (int i = tid; i < 40; i += 256) {
        int r = i / 8, cc = i % 8;
        wsrow[i] = (cc < 5) ? wsm[c * 25 + r * 5 + cc] : 0.f;
    }
    for (int p = tid; p < TROWS * TCOLS; p += 256) {
        int r = p / TCOLS, cl = p % TCOLS;
        int iy = r - PADL, ix = cl - PADL;
        float v = 0.f;
        if (iy >= 0 && iy < HW && ix >= 0 && ix < HW) v = xp[iy * HW + ix];
        tile[p] = v;
    }
    __syncthreads();

    float lsum = 0.f, lss = 0.f;

    if (tid < 196) {
        const int ry = tid / 7, cx = tid % 7;
        const int oy0 = ry * 2;             // output rows oy0, oy0+1
        const int ox0 = cx * 8;             // output cols ox0 .. ox0+7

        float acc0[8], acc1[8];
        #pragma unroll
        for (int o = 0; o < 8; ++o) { acc0[o] = 0.f; acc1[o] = 0.f; }

        float seg[28];
        float wcur[21], wprev[21];
        const f32x4* tile4 = (const f32x4*)tile;
        const f32x4* w4 = (const f32x4*)wrow;
        const f32x4* ws4 = (const f32x4*)wsrow;

        for (int rr = 0; rr < 22; ++rr) {   // input (padded) row = oy0 + rr
            const int r = oy0 + rr;
            // load 28-float segment of this input row
            #pragma unroll
            for (int k = 0; k < 7; ++k) {
                f32x4 v = tile4[r * 20 + 2 * cx + k];
                seg[4 * k + 0] = v[0]; seg[4 * k + 1] = v[1];
                seg[4 * k + 2] = v[2]; seg[4 * k + 3] = v[3];
            }
            // load large-conv weight row rr (if valid)
            if (rr < 21) {
                #pragma unroll
                for (int k = 0; k < 6; ++k) {
                    f32x4 v = w4[rr * 6 + k];
                    #pragma unroll
                    for (int j = 0; j < 4; ++j) {
                        int idx = 4 * k + j;
                        if (idx < 21) wcur[idx] = v[j];
                    }
                }
            }
            // output row 1 uses previous weight row (dy = rr-1)
            if (rr >= 1) {
                #pragma unroll
                for (int dx = 0; dx < 21; ++dx)
                    #pragma unroll
                    for (int o = 0; o < 8; ++o)
                        acc1[o] = fmaf(wprev[dx], seg[dx + o], acc1[o]);
            }
            // output row 0 uses current weight row (dy = rr)
            if (rr < 21) {
                #pragma unroll
                for (int dx = 0; dx < 21; ++dx)
                    #pragma unroll
                    for (int o = 0; o < 8; ++o)
                        acc0[o] = fmaf(wcur[dx], seg[dx + o], acc0[o]);
            }
            // small conv: center offset +8 in padded coords
            if (rr >= 8 && rr < 13) {
                float wsr[8];
                f32x4 a = ws4[(rr - 8) * 2 + 0], b = ws4[(rr - 8) * 2 + 1];
                wsr[0]=a[0]; wsr[1]=a[1]; wsr[2]=a[2]; wsr[3]=a[3];
                wsr[4]=b[0]; wsr[5]=b[1]; wsr[6]=b[2]; wsr[7]=b[3];
                #pragma unroll
                for (int dx = 0; dx < 5; ++dx)
                    #pragma unroll
                    for (int o = 0; o < 8; ++o)
                        acc0[o] = fmaf(wsr[dx], seg[8 + dx + o], acc0[o]);
            }
            if (rr >= 9 && rr < 14) {
                float wsr[8];
                f32x4 a = ws4[(rr - 9) * 2 + 0], b = ws4[(rr - 9) * 2 + 1];
                wsr[0]=a[0]; wsr[1]=a[1]; wsr[2]=a[2]; wsr[3]=a[3];
                wsr[4]=b[0]; wsr[5]=b[1]; wsr[6]=b[2]; wsr[7]=b[3];
                #pragma unroll
                for (int dx = 0; dx < 5; ++dx)
                    #pragma unroll
                    for (int o = 0; o < 8; ++o)
                        acc1[o] = fmaf(wsr[dx], seg[8 + dx + o], acc1[o]);
            }
            // roll weights
            #pragma unroll
            for (int j = 0; j < 21; ++j) wprev[j] = wcur[j];
        }

        // write outputs + accumulate stats
        float* trow = tmp + (size_t)bid * NPIX + oy0 * HW + ox0;
        f32x4 o00, o01, o10, o11;
        o00[0]=acc0[0]; o00[1]=acc0[1]; o00[2]=acc0[2]; o00[3]=acc0[3];
        o01[0]=acc0[4]; o01[1]=acc0[5]; o01[2]=acc0[6]; o01[3]=acc0[7];
        o10[0]=acc1[0]; o10[1]=acc1[1]; o10[2]=acc1[2]; o10[3]=acc1[3];
        o11[0]=acc1[4]; o11[1]=acc1[5]; o11[2]=acc1[6]; o11[3]=acc1[7];
        *(f32x4*)(trow + 0)      = o00;
        *(f32x4*)(trow + 4)      = o01;
        *(f32x4*)(trow + HW)     = o10;
        *(f32x4*)(trow + HW + 4) = o11;
        #pragma unroll
        for (int o = 0; o < 8; ++o) {
            lsum += acc0[o] + acc1[o];
            lss  += acc0[o] * acc0[o] + acc1[o] * acc1[o];
        }
    }

    // block reduction (inactive threads contribute 0)
    #pragma unroll
    for (int off = 32; off > 0; off >>= 1) {
        lsum += __shfl_down(lsum, off);
        lss  += __shfl_down(lss, off);
    }
    const int wv = tid >> 6;
    if ((tid & 63) == 0) { red[wv * 2] = lsum; red[wv * 2 + 1] = lss; }
    __syncthreads();
    if (tid == 0) {
        float s = red[0] + red[2] + red[4] + red[6];
        float ss = red[1] + red[3] + red[5] + red[7];
        partials[2 * bid + 0] = s;
        partials[2 * bid + 1] = ss;
    }
}

// -------- Kernel B: per-sample mean / rstd --------
__global__ void stats_kernel(const float* __restrict__ partials, float* __restrict__ stats) {
    const int n = blockIdx.x;
    const int t = threadIdx.x;   // 64 threads
    float s = 0.f, ss = 0.f;
    for (int c = t; c < DIM; c += 64) {
        s  += partials[2 * (n * DIM + c) + 0];
        ss += partials[2 * (n * DIM + c) + 1];
    }
    #pragma unroll
    for (int off = 32; off > 0; off >>= 1) {
        s  += __shfl_down(s, off);
        ss += __shfl_down(ss, off);
    }
    if (t == 0) {
        const float inv = 1.f / 602112.f;   // DIM*HW*HW
        float mean = s * inv;
        float var = ss * inv - mean * mean;
        stats[2 * n + 0] = mean;
        stats[2 * n + 1] = rsqrtf(var + GN_EPS);
    }
}

// -------- Kernel C: normalize + GELU + 1x1 conv (MFMA) + bias + residual --------
__global__ __launch_bounds__(192)
void pw_kernel(const float* __restrict__ tmp, const float* __restrict__ x,
               const float* __restrict__ gamma, const float* __restrict__ beta,
               const __bf16* __restrict__ wb, const float* __restrict__ bpw,
               const float* __restrict__ stats, float* __restrict__ out) {
    __shared__ __bf16 g_lds[16 * 200];   // [px][ci], row stride 200 bf16 = 400 B

    const int bid = blockIdx.x;
    const int n = bid / 196;             // 196 pixel-tiles per sample
    const int pt = bid % 196;
    const int px0 = pt * 16;
    const int t = threadIdx.x;           // 192 threads = 3 waves; t == ci for staging

    const float mean = stats[2 * n + 0];
    const float rstd = stats[2 * n + 1];

    {
        const float a = rstd * gamma[t];
        const float b = beta[t] - mean * a;
        const float* tp = tmp + ((size_t)n * DIM + t) * NPIX + px0;
        #pragma unroll
        for (int k = 0; k < 4; ++k) {
            f32x4 v = *(const f32x4*)(tp + 4 * k);
            #pragma unroll
            for (int j = 0; j < 4; ++j) {
                float y = v[j] * a + b;
                float g = 0.5f * y * (1.f + erff(y * 0.70710678118654752f));
                g_lds[(4 * k + j) * 200 + t] = (__bf16)g;
            }
        }
    }
    __syncthreads();

    const int w = t >> 6;                // wave id 0..2 -> co block of 64
    const int l = t & 63;
    const int lane16 = l & 15, lg = l >> 4;

    f32x4 acc[4];
    #pragma unroll
    for (int m = 0; m < 4; ++m) { acc[m][0]=0.f; acc[m][1]=0.f; acc[m][2]=0.f; acc[m][3]=0.f; }

    const char* gbase = (const char*)g_lds;
    #pragma unroll
    for (int kk = 0; kk < 6; ++kk) {
        const int k0 = 32 * kk;
        bf16x8 bfrag = *(const bf16x8*)(gbase + lane16 * 400 + (k0 + 8 * lg) * 2);
        #pragma unroll
        for (int m = 0; m < 4; ++m) {
            const int co = 64 * w + 16 * m + lane16;
            bf16x8 afrag = *(const bf16x8*)(wb + co * DIM + k0 + 8 * lg);
            acc[m] = __builtin_amdgcn_mfma_f32_16x16x32_bf16(afrag, bfrag, acc[m], 0, 0, 0);
        }
    }

    const float* xb = x + (size_t)n * DIM * NPIX;
    float* ob = out + (size_t)n * DIM * NPIX;
    #pragma unroll
    for (int m = 0; m < 4; ++m) {
        #pragma unroll
        for (int j = 0; j < 4; ++j) {
            const int co = 64 * w + 16 * m + 4 * lg + j;
            const int idx = co * NPIX + px0 + lane16;
            ob[idx] = acc[m][j] + bpw[co] + xb[idx];
        }
    }
}

extern "C" void kernel_launch(void* const* d_in, const int* in_sizes, int n_in,
                              void* d_out, int out_size, void* d_ws, size_t ws_size,
                              hipStream_t stream) {
    (void)in_sizes; (void)n_in; (void)out_size; (void)ws_size;
    const float* x     = (const float*)d_in[0];
    const float* wl    = (const float*)d_in[1];
    const float* wsm   = (const float*)d_in[2];
    const float* gamma = (const float*)d_in[3];
    const float* beta  = (const float*)d_in[4];
    const float* wpw   = (const float*)d_in[5];
    const float* bpw   = (const float*)d_in[6];
    float* out = (float*)d_out;

    char* wsb = (char*)d_ws;
    float* tmp      = (float*)wsb;
    float* partials = (float*)(wsb + WS_OFF_PARTIALS);
    float* stats    = (float*)(wsb + WS_OFF_STATS);
    __bf16* wb      = (__bf16*)(wsb + WS_OFF_WB);

    conv_w_kernel<<<144, 256, 0, stream>>>(wpw, wb);
    dwconv_kernel<<<NSAMP * DIM, 256, 0, stream>>>(x, wl, wsm, tmp, partials);
    stats_kernel<<<NSAMP, 64, 0, stream>>>(partials, stats);
    pw_kernel<<<NSAMP * 196, 192, 0, stream>>>(tmp, x, gamma, beta, wb, bpw, stats, out);
}

// Round 2
// 189.014 us; speedup vs baseline: 1.0319x; 1.0319x over previous
//
#include <hip/hip_runtime.h>
#include <math.h>

#define DIM 192
#define HW 56
#define NPIX 3136        // 56*56
#define NSAMP 16
#define GN_EPS 1e-5f

#define TROWS 76         // 56 + 2*10
#define STH 88           // tile row stride in halves
#define STB 176          // tile row stride in bytes
#define STW 44           // tile row stride in dwords

typedef float f32x2 __attribute__((ext_vector_type(2)));
typedef float f32x4 __attribute__((ext_vector_type(4)));
typedef unsigned int u32x4 __attribute__((ext_vector_type(4)));
typedef _Float16 h2 __attribute__((ext_vector_type(2)));
typedef __bf16 bf16x8 __attribute__((ext_vector_type(8)));

// ---------------- ws layout (bytes) ----------------
// tmp      : 9,633,792 f32  @ 0            (38,535,168 B)
// partials : 3072*2 f32     @ 38,535,168   (24,576 B)
// stats    : 32 f32         @ 38,559,744   (128 B)
// wb       : 36,864 bf16    @ 38,559,872   (73,728 B)
#define WS_OFF_PARTIALS 38535168
#define WS_OFF_STATS    38559744
#define WS_OFF_WB       38559872

__device__ __forceinline__ unsigned int pack_h2(float a, float b) {
    h2 h;
    h[0] = (_Float16)a;
    h[1] = (_Float16)b;
    return __builtin_bit_cast(unsigned int, h);
}
__device__ __forceinline__ h2 as_h2(unsigned int u) {
    return __builtin_bit_cast(h2, u);
}

// -------- Kernel P: cast pointwise weights to bf16 --------
__global__ void conv_w_kernel(const float* __restrict__ w, __bf16* __restrict__ wb) {
    int i = blockIdx.x * 256 + threadIdx.x;
    if (i < DIM * DIM) wb[i] = (__bf16)w[i];
}

// -------- Kernel A: fused depthwise 21x21 + 5x5 conv via v_dot2_f32_f16 --------
// 448 threads = 7 waves. Thread t: output row r = t>>3 (0..55), col group c = t&7
// (cols 8c..8c+7; c==7 computes garbage cols 56..63, excluded from store/stats).
// f16 tile [76][88 halves]; 8-lane groups read contiguous 128B -> conflict-free.
__global__ __launch_bounds__(448)
void dwconv_kernel(const float* __restrict__ x,
                   const float* __restrict__ wl,
                   const float* __restrict__ wsm,
                   float* __restrict__ tmp,
                   float* __restrict__ partials) {
    __shared__ unsigned int tile[TROWS * STW];   // 13,376 B
    __shared__ unsigned int wp_lds[21 * 12];     // 21 rows x 12 h2-pairs (11 used)
    __shared__ unsigned int wsp_lds[5 * 4];      // 5 rows x 4 h2-pairs (3 used)
    __shared__ float red[14];

    const int bid = blockIdx.x;                  // n*DIM + ch
    const int ch = bid % DIM;
    const int t = threadIdx.x;
    const float* xp = x + (size_t)bid * NPIX;

    // stage large-conv weights as f16 pairs: wp[dy][p] = (w[dy][2p], w[dy][2p+1])
    for (int i = t; i < 21 * 12; i += 448) {
        int dy = i / 12, p = i % 12;
        float w0 = (2 * p < 21) ? wl[ch * 441 + dy * 21 + 2 * p] : 0.f;
        float w1 = (2 * p + 1 < 21) ? wl[ch * 441 + dy * 21 + 2 * p + 1] : 0.f;
        wp_lds[i] = pack_h2(w0, w1);
    }
    // small-conv weights
    if (t < 20) {
        int rr = t / 4, p = t % 4;
        float w0 = (2 * p < 5) ? wsm[ch * 25 + rr * 5 + 2 * p] : 0.f;
        float w1 = (2 * p + 1 < 5) ? wsm[ch * 25 + rr * 5 + 2 * p + 1] : 0.f;
        wsp_lds[t] = pack_h2(w0, w1);
    }
    // stage input tile as f16 pairs. dword d=(R,W): halves 2W,2W+1 = padded cols,
    // input row R-10, input cols 2W-10, 2W-9; fully valid iff R in [10,66) and W in [5,32].
    for (int d = t; d < TROWS * STW; d += 448) {
        int R = d / STW, W = d % STW;
        unsigned int v = 0;
        if (R >= 10 && R < 66 && W >= 5 && W <= 32) {
            f32x2 p2 = *(const f32x2*)(xp + (R - 10) * HW + (2 * W - 10));
            v = pack_h2(p2[0], p2[1]);
        }
        tile[d] = v;
    }
    __syncthreads();

    const int r = t >> 3;       // output row
    const int c = t & 7;        // col group

    float acc[8];
    #pragma unroll
    for (int o = 0; o < 8; ++o) acc[o] = 0.f;

    const char* tb = (const char*)tile + c * 16;

    for (int dy = 0; dy < 21; ++dy) {
        const char* rb = tb + (r + dy) * STB;
        u32x4 q0 = *(const u32x4*)(rb);
        u32x4 q1 = *(const u32x4*)(rb + 16);
        u32x4 q2 = *(const u32x4*)(rb + 32);
        u32x4 q3 = *(const u32x4*)(rb + 48);
        unsigned int e[16];
        e[0]=q0[0];  e[1]=q0[1];  e[2]=q0[2];  e[3]=q0[3];
        e[4]=q1[0];  e[5]=q1[1];  e[6]=q1[2];  e[7]=q1[3];
        e[8]=q2[0];  e[9]=q2[1];  e[10]=q2[2]; e[11]=q2[3];
        e[12]=q3[0]; e[13]=q3[1]; e[14]=q3[2]; e[15]=q3[3];
        // odd-aligned pairs: od[k] = (s[2k+1], s[2k+2])
        unsigned int od[14];
        #pragma unroll
        for (int k = 0; k < 14; ++k)
            od[k] = __builtin_amdgcn_alignbit(e[k + 1], e[k], 16);

        const u32x4* wrow = (const u32x4*)(wp_lds + dy * 12);
        u32x4 a0 = wrow[0], a1 = wrow[1], a2 = wrow[2];
        unsigned int wp[11];
        wp[0]=a0[0]; wp[1]=a0[1]; wp[2]=a0[2]; wp[3]=a0[3];
        wp[4]=a1[0]; wp[5]=a1[1]; wp[6]=a1[2]; wp[7]=a1[3];
        wp[8]=a2[0]; wp[9]=a2[1]; wp[10]=a2[2];

        #pragma unroll
        for (int o = 0; o < 8; ++o) {
            #pragma unroll
            for (int p = 0; p <= 10; ++p) {
                unsigned int pr = (o & 1) ? od[p + (o >> 1)] : e[p + (o >> 1)];
                acc[o] = __builtin_amdgcn_fdot2(as_h2(wp[p]), as_h2(pr), acc[o], false);
            }
        }
        // small 5x5 conv: active for dy in [8,12], taps at seg offset 8+dx'
        if (dy >= 8 && dy <= 12) {
            u32x4 ws4 = *(const u32x4*)(wsp_lds + (dy - 8) * 4);
            #pragma unroll
            for (int o = 0; o < 8; ++o) {
                #pragma unroll
                for (int p = 0; p < 3; ++p) {
                    unsigned int pr = (o & 1) ? od[4 + p + (o >> 1)] : e[4 + p + (o >> 1)];
                    acc[o] = __builtin_amdgcn_fdot2(as_h2(ws4[p]), as_h2(pr), acc[o], false);
                }
            }
        }
    }

    float lsum = 0.f, lss = 0.f;
    if (c < 7) {
        float* trow = tmp + (size_t)bid * NPIX + r * HW + 8 * c;
        f32x4 v0, v1;
        v0[0]=acc[0]; v0[1]=acc[1]; v0[2]=acc[2]; v0[3]=acc[3];
        v1[0]=acc[4]; v1[1]=acc[5]; v1[2]=acc[6]; v1[3]=acc[7];
        *(f32x4*)trow = v0;
        *(f32x4*)(trow + 4) = v1;
        #pragma unroll
        for (int o = 0; o < 8; ++o) { lsum += acc[o]; lss += acc[o] * acc[o]; }
    }

    #pragma unroll
    for (int off = 32; off > 0; off >>= 1) {
        lsum += __shfl_down(lsum, off);
        lss  += __shfl_down(lss, off);
    }
    const int wv = t >> 6;
    if ((t & 63) == 0) { red[wv * 2] = lsum; red[wv * 2 + 1] = lss; }
    __syncthreads();
    if (t == 0) {
        float s = 0.f, ss = 0.f;
        #pragma unroll
        for (int w = 0; w < 7; ++w) { s += red[2 * w]; ss += red[2 * w + 1]; }
        partials[2 * bid + 0] = s;
        partials[2 * bid + 1] = ss;
    }
}

// -------- Kernel B: per-sample mean / rstd --------
__global__ void stats_kernel(const float* __restrict__ partials, float* __restrict__ stats) {
    const int n = blockIdx.x;
    const int t = threadIdx.x;   // 64 threads
    float s = 0.f, ss = 0.f;
    for (int c = t; c < DIM; c += 64) {
        s  += partials[2 * (n * DIM + c) + 0];
        ss += partials[2 * (n * DIM + c) + 1];
    }
    #pragma unroll
    for (int off = 32; off > 0; off >>= 1) {
        s  += __shfl_down(s, off);
        ss += __shfl_down(ss, off);
    }
    if (t == 0) {
        const float inv = 1.f / 602112.f;   // DIM*HW*HW
        float mean = s * inv;
        float var = ss * inv - mean * mean;
        stats[2 * n + 0] = mean;
        stats[2 * n + 1] = rsqrtf(var + GN_EPS);
    }
}

// -------- Kernel C: normalize + GELU + 1x1 conv (MFMA) + bias + residual --------
__global__ __launch_bounds__(192)
void pw_kernel(const float* __restrict__ tmp, const float* __restrict__ x,
               const float* __restrict__ gamma, const float* __restrict__ beta,
               const __bf16* __restrict__ wb, const float* __restrict__ bpw,
               const float* __restrict__ stats, float* __restrict__ out) {
    __shared__ __bf16 g_lds[16 * 200];   // [px][ci], row stride 200 bf16 = 400 B

    const int bid = blockIdx.x;
    const int n = bid / 196;             // 196 pixel-tiles per sample
    const int pt = bid % 196;
    const int px0 = pt * 16;
    const int t = threadIdx.x;           // 192 threads = 3 waves; t == ci for staging

    const float mean = stats[2 * n + 0];
    const float rstd = stats[2 * n + 1];

    {
        const float a = rstd * gamma[t];
        const float b = beta[t] - mean * a;
        const float* tp = tmp + ((size_t)n * DIM + t) * NPIX + px0;
        #pragma unroll
        for (int k = 0; k < 4; ++k) {
            f32x4 v = *(const f32x4*)(tp + 4 * k);
            #pragma unroll
            for (int j = 0; j < 4; ++j) {
                float y = v[j] * a + b;
                float g = 0.5f * y * (1.f + erff(y * 0.70710678118654752f));
                g_lds[(4 * k + j) * 200 + t] = (__bf16)g;
            }
        }
    }
    __syncthreads();

    const int w = t >> 6;                // wave id 0..2 -> co block of 64
    const int l = t & 63;
    const int lane16 = l & 15, lg = l >> 4;

    f32x4 acc[4];
    #pragma unroll
    for (int m = 0; m < 4; ++m) { acc[m][0]=0.f; acc[m][1]=0.f; acc[m][2]=0.f; acc[m][3]=0.f; }

    const char* gbase = (const char*)g_lds;
    #pragma unroll
    for (int kk = 0; kk < 6; ++kk) {
        const int k0 = 32 * kk;
        bf16x8 bfrag = *(const bf16x8*)(gbase + lane16 * 400 + (k0 + 8 * lg) * 2);
        #pragma unroll
        for (int m = 0; m < 4; ++m) {
            const int co = 64 * w + 16 * m + lane16;
            bf16x8 afrag = *(const bf16x8*)(wb + co * DIM + k0 + 8 * lg);
            acc[m] = __builtin_amdgcn_mfma_f32_16x16x32_bf16(afrag, bfrag, acc[m], 0, 0, 0);
        }
    }

    const float* xb = x + (size_t)n * DIM * NPIX;
    float* ob = out + (size_t)n * DIM * NPIX;
    #pragma unroll
    for (int m = 0; m < 4; ++m) {
        #pragma unroll
        for (int j = 0; j < 4; ++j) {
            const int co = 64 * w + 16 * m + 4 * lg + j;
            const int idx = co * NPIX + px0 + lane16;
            ob[idx] = acc[m][j] + bpw[co] + xb[idx];
        }
    }
}

extern "C" void kernel_launch(void* const* d_in, const int* in_sizes, int n_in,
                              void* d_out, int out_size, void* d_ws, size_t ws_size,
                              hipStream_t stream) {
    (void)in_sizes; (void)n_in; (void)out_size; (void)ws_size;
    const float* x     = (const float*)d_in[0];
    const float* wl    = (const float*)d_in[1];
    const float* wsm   = (const float*)d_in[2];
    const float* gamma = (const float*)d_in[3];
    const float* beta  = (const float*)d_in[4];
    const float* wpw   = (const float*)d_in[5];
    const float* bpw   = (const float*)d_in[6];
    float* out = (float*)d_out;

    char* wsb = (char*)d_ws;
    float* tmp      = (float*)wsb;
    float* partials = (float*)(wsb + WS_OFF_PARTIALS);
    float* stats    = (float*)(wsb + WS_OFF_STATS);
    __bf16* wb      = (__bf16*)(wsb + WS_OFF_WB);

    conv_w_kernel<<<144, 256, 0, stream>>>(wpw, wb);
    dwconv_kernel<<<NSAMP * DIM, 448, 0, stream>>>(x, wl, wsm, tmp, partials);
    stats_kernel<<<NSAMP, 64, 0, stream>>>(partials, stats);
    pw_kernel<<<NSAMP * 196, 192, 0, stream>>>(tmp, x, gamma, beta, wb, bpw, stats, out);
}

// Round 3
// 160.924 us; speedup vs baseline: 1.2121x; 1.1746x over previous
//
#include <hip/hip_runtime.h>
#include <math.h>

#define DIM 192
#define HW 56
#define NPIX 3136        // 56*56
#define NSAMP 16
#define GN_EPS 1e-5f

#define TROWS 76         // 56 + 2*10
#define STW 44           // tile row stride in dwords (88 halves)
#define STB 176          // tile row stride in bytes
#define TILE_DW (TROWS * STW)   // 3344 dwords per channel tile

typedef float f32x2 __attribute__((ext_vector_type(2)));
typedef float f32x4 __attribute__((ext_vector_type(4)));
typedef unsigned int u32x4 __attribute__((ext_vector_type(4)));
typedef _Float16 h2 __attribute__((ext_vector_type(2)));
typedef __bf16 bf16x8 __attribute__((ext_vector_type(8)));

// ---------------- ws layout (bytes) ----------------
#define WS_OFF_PARTIALS 38535168
#define WS_OFF_STATS    38559744
#define WS_OFF_WB       38559872

__device__ __forceinline__ unsigned int pack_h2(float a, float b) {
    h2 h;
    h[0] = (_Float16)a;
    h[1] = (_Float16)b;
    return __builtin_bit_cast(unsigned int, h);
}
__device__ __forceinline__ h2 as_h2(unsigned int u) {
    return __builtin_bit_cast(h2, u);
}

// -------- Kernel P: cast pointwise weights to bf16 --------
__global__ void conv_w_kernel(const float* __restrict__ w, __bf16* __restrict__ wb) {
    int i = blockIdx.x * 256 + threadIdx.x;
    if (i < DIM * DIM) wb[i] = (__bf16)w[i];
}

// -------- Kernel A: fused depthwise 21x21 + 5x5 conv via v_dot2_f32_f16 --------
// Block = 4 channels x 224 threads = 896 threads (14 waves).
// Per channel: thread u (0..223): row-pair rbase = (u>>3)*2, col group c = u&7.
// Each thread computes 2 output rows x 8 cols; one LDS row-segment read serves
// both rows (dy=rr for row0 via wcur, dy=rr-1 for row1 via wprev rolling regs).
__global__ __launch_bounds__(896)
void dwconv_kernel(const float* __restrict__ x,
                   const float* __restrict__ wl,
                   const float* __restrict__ wsm,
                   float* __restrict__ tmp,
                   float* __restrict__ partials) {
    __shared__ unsigned int tile[4 * TILE_DW];   // 53,504 B
    __shared__ unsigned int wp_lds[4 * 252];     // 4 ch x 21 rows x 12 h2-pairs
    __shared__ unsigned int wsp_lds[4 * 20];     // 4 ch x 5 rows x 4 h2-pairs
    __shared__ float red[56];                    // 28 x (sum, ss)

    const int bid = blockIdx.x;
    const int t = threadIdx.x;
    const int p0 = bid * 4;                      // first plane (n*DIM + c)

    // stage large-conv weights as f16 pairs
    for (int i = t; i < 4 * 252; i += 896) {
        int chl = i / 252, j = i - chl * 252;
        int dy = j / 12, p = j - dy * 12;
        int cg = (p0 + chl) % DIM;
        float w0 = (2 * p < 21) ? wl[cg * 441 + dy * 21 + 2 * p] : 0.f;
        float w1 = (2 * p + 1 < 21) ? wl[cg * 441 + dy * 21 + 2 * p + 1] : 0.f;
        wp_lds[i] = pack_h2(w0, w1);
    }
    // small-conv weights
    if (t < 80) {
        int chl = t / 20, j = t - chl * 20;
        int rr = j >> 2, p = j & 3;
        int cg = (p0 + chl) % DIM;
        float w0 = (2 * p < 5) ? wsm[cg * 25 + rr * 5 + 2 * p] : 0.f;
        float w1 = (2 * p + 1 < 5) ? wsm[cg * 25 + rr * 5 + 2 * p + 1] : 0.f;
        wsp_lds[t] = pack_h2(w0, w1);
    }
    // stage input tiles as f16 pairs (zero-padded halo)
    for (int d = t; d < 4 * TILE_DW; d += 896) {
        int chl = d / TILE_DW, dd = d - chl * TILE_DW;
        int R = dd / STW, W = dd - R * STW;
        unsigned int v = 0;
        if (R >= 10 && R < 66 && W >= 5 && W <= 32) {
            const float* xp = x + (size_t)(p0 + chl) * NPIX;
            f32x2 q = *(const f32x2*)(xp + (R - 10) * HW + (2 * W - 10));
            v = pack_h2(q[0], q[1]);
        }
        tile[d] = v;
    }
    __syncthreads();

    const int ch = t / 224;
    const int u = t - ch * 224;
    const int rbase = (u >> 3) * 2;   // output rows rbase, rbase+1
    const int c = u & 7;              // output cols 8c..8c+7 (c==7 garbage)

    const char* tb = (const char*)(tile + ch * TILE_DW) + c * 16;
    const u32x4* wrow4 = (const u32x4*)(wp_lds + ch * 252);
    const u32x4* wsrow4 = (const u32x4*)(wsp_lds + ch * 20);

    float acc0[8], acc1[8];
    #pragma unroll
    for (int o = 0; o < 8; ++o) { acc0[o] = 0.f; acc1[o] = 0.f; }

    unsigned int e[16], od[14];
    unsigned int wA[11], wB[11];

    auto loadseg = [&](int R) {
        const u32x4* rp = (const u32x4*)(tb + R * STB);
        u32x4 q0 = rp[0], q1 = rp[1], q2 = rp[2], q3 = rp[3];
        e[0]=q0[0];  e[1]=q0[1];  e[2]=q0[2];  e[3]=q0[3];
        e[4]=q1[0];  e[5]=q1[1];  e[6]=q1[2];  e[7]=q1[3];
        e[8]=q2[0];  e[9]=q2[1];  e[10]=q2[2]; e[11]=q2[3];
        e[12]=q3[0]; e[13]=q3[1]; e[14]=q3[2]; e[15]=q3[3];
        #pragma unroll
        for (int k = 0; k < 14; ++k)
            od[k] = __builtin_amdgcn_alignbit(e[k + 1], e[k], 16);
    };
    auto loadw = [&](unsigned int* w, int rr) {
        u32x4 a0 = wrow4[rr * 3], a1 = wrow4[rr * 3 + 1], a2 = wrow4[rr * 3 + 2];
        w[0]=a0[0]; w[1]=a0[1]; w[2]=a0[2]; w[3]=a0[3];
        w[4]=a1[0]; w[5]=a1[1]; w[6]=a1[2]; w[7]=a1[3];
        w[8]=a2[0]; w[9]=a2[1]; w[10]=a2[2];
    };
    auto dot21 = [&](float* acc, const unsigned int* w) {
        #pragma unroll
        for (int o = 0; o < 8; ++o)
            #pragma unroll
            for (int p = 0; p <= 10; ++p) {
                unsigned int pr = (o & 1) ? od[p + (o >> 1)] : e[p + (o >> 1)];
                acc[o] = __builtin_amdgcn_fdot2(as_h2(w[p]), as_h2(pr), acc[o], false);
            }
    };
    auto dot5 = [&](float* acc, int srow) {
        u32x4 s4 = wsrow4[srow];
        #pragma unroll
        for (int o = 0; o < 8; ++o)
            #pragma unroll
            for (int p = 0; p < 3; ++p) {
                unsigned int pr = (o & 1) ? od[4 + p + (o >> 1)] : e[4 + p + (o >> 1)];
                acc[o] = __builtin_amdgcn_fdot2(as_h2(s4[p]), as_h2(pr), acc[o], false);
            }
    };

    // rr = 0 (acc0 only)
    loadseg(rbase);
    loadw(wA, 0);
    dot21(acc0, wA);

    #pragma unroll 1
    for (int it = 0; it < 10; ++it) {
        const int rr1 = 2 * it + 1;            // odd row
        loadseg(rbase + rr1);
        loadw(wB, rr1);
        dot21(acc1, wA);                        // dy = rr1-1 (even)
        dot21(acc0, wB);                        // dy = rr1
        if (rr1 >= 9 && rr1 <= 11) dot5(acc0, rr1 - 8);   // rr1 in {9,11}
        if (rr1 >= 9 && rr1 <= 13) dot5(acc1, rr1 - 9);   // rr1 in {9,11,13}

        const int rr2 = 2 * it + 2;            // even row (<= 20)
        loadseg(rbase + rr2);
        loadw(wA, rr2);
        dot21(acc1, wB);                        // dy = rr2-1 (odd)
        dot21(acc0, wA);                        // dy = rr2
        if (rr2 >= 8 && rr2 <= 12) dot5(acc0, rr2 - 8);   // rr2 in {8,10,12}
        if (rr2 >= 10 && rr2 <= 12) dot5(acc1, rr2 - 9);  // rr2 in {10,12}
    }
    // rr = 21 (acc1 only, dy = 20 held in wA)
    loadseg(rbase + 21);
    dot21(acc1, wA);

    float lsum = 0.f, lss = 0.f;
    if (c < 7) {
        float* trow = tmp + (size_t)(p0 + ch) * NPIX + rbase * HW + 8 * c;
        f32x4 v0, v1, v2, v3;
        v0[0]=acc0[0]; v0[1]=acc0[1]; v0[2]=acc0[2]; v0[3]=acc0[3];
        v1[0]=acc0[4]; v1[1]=acc0[5]; v1[2]=acc0[6]; v1[3]=acc0[7];
        v2[0]=acc1[0]; v2[1]=acc1[1]; v2[2]=acc1[2]; v2[3]=acc1[3];
        v3[0]=acc1[4]; v3[1]=acc1[5]; v3[2]=acc1[6]; v3[3]=acc1[7];
        *(f32x4*)trow = v0;
        *(f32x4*)(trow + 4) = v1;
        *(f32x4*)(trow + HW) = v2;
        *(f32x4*)(trow + HW + 4) = v3;
        #pragma unroll
        for (int o = 0; o < 8; ++o) {
            lsum += acc0[o] + acc1[o];
            lss  += acc0[o] * acc0[o] + acc1[o] * acc1[o];
        }
    }

    // reduce within 32-lane groups (each group is single-channel: 224 = 7*32)
    #pragma unroll
    for (int off = 16; off > 0; off >>= 1) {
        lsum += __shfl_down(lsum, off, 32);
        lss  += __shfl_down(lss, off, 32);
    }
    const int grp = t >> 5;
    if ((t & 31) == 0) { red[grp * 2] = lsum; red[grp * 2 + 1] = lss; }
    __syncthreads();
    if (t < 4) {
        float s = 0.f, ss = 0.f;
        #pragma unroll
        for (int g = 0; g < 7; ++g) {
            s  += red[2 * (t * 7 + g)];
            ss += red[2 * (t * 7 + g) + 1];
        }
        partials[2 * (p0 + t) + 0] = s;
        partials[2 * (p0 + t) + 1] = ss;
    }
}

// -------- Kernel B: per-sample mean / rstd --------
__global__ void stats_kernel(const float* __restrict__ partials, float* __restrict__ stats) {
    const int n = blockIdx.x;
    const int t = threadIdx.x;   // 64 threads
    float s = 0.f, ss = 0.f;
    for (int c = t; c < DIM; c += 64) {
        s  += partials[2 * (n * DIM + c) + 0];
        ss += partials[2 * (n * DIM + c) + 1];
    }
    #pragma unroll
    for (int off = 32; off > 0; off >>= 1) {
        s  += __shfl_down(s, off);
        ss += __shfl_down(ss, off);
    }
    if (t == 0) {
        const float inv = 1.f / 602112.f;   // DIM*HW*HW
        float mean = s * inv;
        float var = ss * inv - mean * mean;
        stats[2 * n + 0] = mean;
        stats[2 * n + 1] = rsqrtf(var + GN_EPS);
    }
}

// fast exact-GELU via Abramowitz-Stegun 7.1.26 erf (|err| <= 1.5e-7)
__device__ __forceinline__ float fast_gelu(float y) {
    float z = fabsf(y) * 0.70710678118654752f;
    float tt = __builtin_amdgcn_rcpf(1.f + 0.3275911f * z);
    float poly = tt * (0.254829592f + tt * (-0.284496736f + tt * (1.421413741f
               + tt * (-1.453152027f + tt * 1.061405429f))));
    float er = 1.f - poly * __expf(-z * z);
    er = copysignf(er, y);
    return 0.5f * y * (1.f + er);
}

// -------- Kernel C: normalize + GELU + 1x1 conv (MFMA) + bias + residual --------
// Block = 192 threads (3 waves), 32 pixels. Wave w: co 64w..64w+63, 2 px subtiles.
__global__ __launch_bounds__(192)
void pw_kernel(const float* __restrict__ tmp, const float* __restrict__ x,
               const float* __restrict__ gamma, const float* __restrict__ beta,
               const __bf16* __restrict__ wb, const float* __restrict__ bpw,
               const float* __restrict__ stats, float* __restrict__ out) {
    __shared__ __bf16 g_lds[32 * 200];   // [px][ci], row stride 200 bf16

    const int bid = blockIdx.x;
    const int n = bid / 98;              // 98 pixel-tiles of 32 per sample
    const int pt = bid - n * 98;
    const int px0 = pt * 32;
    const int t = threadIdx.x;           // t == ci for staging

    const float mean = stats[2 * n + 0];
    const float rstd = stats[2 * n + 1];

    {
        const float a = rstd * gamma[t];
        const float b = beta[t] - mean * a;
        const float* tp = tmp + ((size_t)n * DIM + t) * NPIX + px0;
        #pragma unroll
        for (int k = 0; k < 8; ++k) {
            f32x4 v = *(const f32x4*)(tp + 4 * k);
            #pragma unroll
            for (int j = 0; j < 4; ++j) {
                float y = v[j] * a + b;
                g_lds[(4 * k + j) * 200 + t] = (__bf16)fast_gelu(y);
            }
        }
    }
    __syncthreads();

    const int w = t >> 6;                // wave id -> co block of 64
    const int l = t & 63;
    const int lane16 = l & 15, lg = l >> 4;

    f32x4 acc[2][4];
    #pragma unroll
    for (int p = 0; p < 2; ++p)
        #pragma unroll
        for (int m = 0; m < 4; ++m) { acc[p][m][0]=0.f; acc[p][m][1]=0.f; acc[p][m][2]=0.f; acc[p][m][3]=0.f; }

    const char* gbase = (const char*)g_lds;
    #pragma unroll
    for (int kk = 0; kk < 6; ++kk) {
        const int k0 = 32 * kk;
        bf16x8 bf0 = *(const bf16x8*)(gbase + lane16 * 400 + (k0 + 8 * lg) * 2);
        bf16x8 bf1 = *(const bf16x8*)(gbase + (16 + lane16) * 400 + (k0 + 8 * lg) * 2);
        #pragma unroll
        for (int m = 0; m < 4; ++m) {
            const int co = 64 * w + 16 * m + lane16;
            bf16x8 af = *(const bf16x8*)(wb + co * DIM + k0 + 8 * lg);
            acc[0][m] = __builtin_amdgcn_mfma_f32_16x16x32_bf16(af, bf0, acc[0][m], 0, 0, 0);
            acc[1][m] = __builtin_amdgcn_mfma_f32_16x16x32_bf16(af, bf1, acc[1][m], 0, 0, 0);
        }
    }

    const float* xb = x + (size_t)n * DIM * NPIX;
    float* ob = out + (size_t)n * DIM * NPIX;
    #pragma unroll
    for (int m = 0; m < 4; ++m) {
        f32x4 b4 = *(const f32x4*)(bpw + 64 * w + 16 * m + 4 * lg);
        #pragma unroll
        for (int p = 0; p < 2; ++p)
            #pragma unroll
            for (int j = 0; j < 4; ++j) {
                const int co = 64 * w + 16 * m + 4 * lg + j;
                const int idx = co * NPIX + px0 + p * 16 + lane16;
                ob[idx] = acc[p][m][j] + b4[j] + xb[idx];
            }
    }
}

extern "C" void kernel_launch(void* const* d_in, const int* in_sizes, int n_in,
                              void* d_out, int out_size, void* d_ws, size_t ws_size,
                              hipStream_t stream) {
    (void)in_sizes; (void)n_in; (void)out_size; (void)ws_size;
    const float* x     = (const float*)d_in[0];
    const float* wl    = (const float*)d_in[1];
    const float* wsm   = (const float*)d_in[2];
    const float* gamma = (const float*)d_in[3];
    const float* beta  = (const float*)d_in[4];
    const float* wpw   = (const float*)d_in[5];
    const float* bpw   = (const float*)d_in[6];
    float* out = (float*)d_out;

    char* wsb = (char*)d_ws;
    float* tmp      = (float*)wsb;
    float* partials = (float*)(wsb + WS_OFF_PARTIALS);
    float* stats    = (float*)(wsb + WS_OFF_STATS);
    __bf16* wb      = (__bf16*)(wsb + WS_OFF_WB);

    conv_w_kernel<<<144, 256, 0, stream>>>(wpw, wb);
    dwconv_kernel<<<NSAMP * DIM / 4, 896, 0, stream>>>(x, wl, wsm, tmp, partials);
    stats_kernel<<<NSAMP, 64, 0, stream>>>(partials, stats);
    pw_kernel<<<NSAMP * 98, 192, 0, stream>>>(tmp, x, gamma, beta, wb, bpw, stats, out);
}

// Round 5
// 114.423 us; speedup vs baseline: 1.7046x; 1.4064x over previous
//
#include <hip/hip_runtime.h>
#include <math.h>

#define DIM 192
#define HW 56
#define NPIX 3136        // 56*56
#define NSAMP 16
#define GN_EPS 1e-5f

typedef float f32x2 __attribute__((ext_vector_type(2)));
typedef float f32x4 __attribute__((ext_vector_type(4)));
typedef float f32x16 __attribute__((ext_vector_type(16)));
typedef unsigned int u32x4 __attribute__((ext_vector_type(4)));
typedef _Float16 h2 __attribute__((ext_vector_type(2)));
typedef _Float16 h8 __attribute__((ext_vector_type(8)));
typedef __bf16 bf16x8 __attribute__((ext_vector_type(8)));

// ---------------- ws layout (bytes) ----------------
#define WS_OFF_PARTIALS 38535168
#define WS_OFF_STATS    38559744
#define WS_OFF_WB       38559872

__device__ __forceinline__ unsigned int pack_h2(float a, float b) {
    h2 h;
    h[0] = (_Float16)a;
    h[1] = (_Float16)b;
    return __builtin_bit_cast(unsigned int, h);
}

// -------- Kernel P: cast pointwise weights to bf16 --------
__global__ void conv_w_kernel(const float* __restrict__ w, __bf16* __restrict__ wb) {
    int i = blockIdx.x * 256 + threadIdx.x;
    if (i < DIM * DIM) wb[i] = (__bf16)w[i];
}

// ======== Kernel A: skew-MFMA depthwise 21x21 + 5x5 conv ========
// One wave per (n,ch) plane. Tile: 56 rows x 96 halves (f16), 48-dword stride.
// Per input row r (padded, 10..65): D[m][n] = sum_k A[m][k]*B[k][n],
//   A[m][k] = wl[m][k] (m=0..20) / wsm[m-21][k-8] (m=21..25, k=8..12)
//   B[k][n] = tile[r][2n + d' + k], d' in {0,1} -> output x = 2n + d'.
// D row m contributes to output row y = r - q, q = m (large) / m-13 (small).
// Per-lane 21-slot register ring, slot index (r - q) % 21; hi half-wave uses
// renamed slots (y+4)%21 so register->slot maps are compile-time. Emit y=r-20.
// Rows r=10..19 produce junk for y<0 -> masked by QMAX guards (q <= r).
#define S2(PH, t) ((((PH) - (t)) % 21 + 21) % 21)
#define AB16(a, b) __builtin_amdgcn_alignbit((a), (b), 16)

// renamed-slot accumulate; adds only contributions with true q <= QMAX.
// reg j (j=0..15): lo row m=(j&3)+8*(j>>2), hi row m=lo+4.
#define RING_Q(rg, dd, PH, QMAX) do { \
    rg[S2(PH,0)] += dd[0]; \
    rg[S2(PH,1)] += dd[1]; \
    rg[S2(PH,2)] += dd[2]; \
    rg[S2(PH,3)] += dd[3]; \
    if (12 <= (QMAX)) rg[S2(PH,8)]  += dd[4]; else rg[S2(PH,8)]  += hi ? 0.f : dd[4]; \
    if (13 <= (QMAX)) rg[S2(PH,9)]  += dd[5]; else rg[S2(PH,9)]  += hi ? 0.f : dd[5]; \
    if (14 <= (QMAX)) rg[S2(PH,10)] += dd[6]; else rg[S2(PH,10)] += hi ? 0.f : dd[6]; \
    if (15 <= (QMAX)) rg[S2(PH,11)] += dd[7]; \
    else if (11 <= (QMAX)) rg[S2(PH,11)] += hi ? 0.f : dd[7]; \
    if (20 <= (QMAX)) rg[S2(PH,16)] += dd[8]; \
    else if (16 <= (QMAX)) rg[S2(PH,16)] += hi ? 0.f : dd[8]; \
    if (17 <= (QMAX)) rg[S2(PH,17)] += hi ? 0.f : dd[9]; \
    rg[S2(PH,4)] += hi ? dd[9] : 0.f; \
    if (18 <= (QMAX)) rg[S2(PH,18)] += hi ? 0.f : dd[10]; \
    rg[S2(PH,5)] += hi ? dd[10] : 0.f; \
    if (19 <= (QMAX)) rg[S2(PH,19)] += hi ? 0.f : dd[11]; \
    rg[S2(PH,6)] += hi ? dd[11] : 0.f; \
    if (11 <= (QMAX)) rg[S2(PH,11)] += hi ? 0.f : dd[12]; \
    if (12 <= (QMAX)) rg[S2(PH,12)] += hi ? 0.f : dd[13]; \
} while (0)

#define STEP(PH_, QMAX_, RVAL_) do { \
    const unsigned int* rp = base + ((RVAL_) - 10) * 48; \
    unsigned int d0 = rp[0], d1 = rp[1], d2 = rp[2], d3 = rp[3], d4 = rp[4]; \
    unsigned int e0 = rp[8], e1 = rp[9], e2 = rp[10], e3 = rp[11], e4 = rp[12]; \
    { \
        u32x4 q0; q0[0] = d0; q0[1] = d1; q0[2] = d2; q0[3] = d3; \
        u32x4 q1; q1[0] = e0; q1[1] = e1; q1[2] = e2; q1[3] = e3; \
        f32x16 acc = __builtin_amdgcn_mfma_f32_32x32x16_f16( \
            A0, __builtin_bit_cast(h8, q0), CZ, 0, 0, 0); \
        acc = __builtin_amdgcn_mfma_f32_32x32x16_f16( \
            A1, __builtin_bit_cast(h8, q1), acc, 0, 0, 0); \
        RING_Q(ring0, acc, PH_, QMAX_); \
    } \
    { \
        u32x4 q0, q1; \
        q0[0] = AB16(d1, d0); q0[1] = AB16(d2, d1); q0[2] = AB16(d3, d2); q0[3] = AB16(d4, d3); \
        q1[0] = AB16(e1, e0); q1[1] = AB16(e2, e1); q1[2] = AB16(e3, e2); q1[3] = AB16(e4, e3); \
        f32x16 acc = __builtin_amdgcn_mfma_f32_32x32x16_f16( \
            A0, __builtin_bit_cast(h8, q0), CZ, 0, 0, 0); \
        acc = __builtin_amdgcn_mfma_f32_32x32x16_f16( \
            A1, __builtin_bit_cast(h8, q1), acc, 0, 0, 0); \
        RING_Q(ring1, acc, PH_, QMAX_); \
    } \
} while (0)

#define EMIT(PH_, RVAL_) do { \
    const int s0 = S2(PH_, 20), s1 = S2(PH_, 16); \
    float p0 = hi ? ring0[s1] : ring0[s0]; \
    float p1 = hi ? ring1[s1] : ring1[s0]; \
    ring0[s0] = hi ? ring0[s0] : 0.f; \
    ring0[s1] = hi ? 0.f : ring0[s1]; \
    ring1[s0] = hi ? ring1[s0] : 0.f; \
    ring1[s1] = hi ? 0.f : ring1[s1]; \
    float t0 = p0 + __shfl_xor(p0, 32); \
    float t1 = p1 + __shfl_xor(p1, 32); \
    if (!hi && nok) { \
        const int y = (RVAL_) - 20; \
        f32x2 st; st[0] = t0; st[1] = t1; \
        *(f32x2*)(top + y * HW + 2 * n) = st; \
        lsum += t0 + t1; \
        lss += t0 * t0 + t1 * t1; \
    } \
} while (0)

__global__ __launch_bounds__(64, 3)
void dwconv_kernel(const float* __restrict__ x,
                   const float* __restrict__ wl,
                   const float* __restrict__ wsm,
                   float* __restrict__ tmp,
                   float* __restrict__ partials) {
    __shared__ unsigned int tile[56 * 48];   // 10,752 B

    const int plane = blockIdx.x;            // n*DIM + ch
    const int ch = plane % DIM;
    const int l = threadIdx.x;
    const int n = l & 31;
    const int h = l >> 5;
    const bool hi = (h == 1);
    const bool nok = (n < 28);
    const float* xp = x + (size_t)plane * NPIX;

    // zero tile (halo columns)
    {
        u32x4* t4 = (u32x4*)tile;
        for (int i = l; i < 672; i += 64) {
            u32x4 z; z[0] = 0; z[1] = 0; z[2] = 0; z[3] = 0;
            t4[i] = z;
        }
    }
    __syncthreads();
    // fill valid region: dword 5+j of row holds padded cols 10+2j, 11+2j
    for (int i = l; i < 56 * 28; i += 64) {
        int row = i / 28, j = i - row * 28;
        f32x2 v = *(const f32x2*)(xp + row * HW + 2 * j);
        tile[row * 48 + 5 + j] = pack_h2(v[0], v[1]);
    }

    // A-operands (weights): lane = weight row m (=n), element e = tap 8h+e (A0)
    // and 16+8h+e (A1); rows 21..25 carry the 5x5 weights at taps 8..12.
    h8 A0, A1;
    {
        const int m = n;
        #pragma unroll
        for (int e = 0; e < 8; ++e) {
            int tp = 8 * h + e;
            float v0 = 0.f, v1 = 0.f;
            if (m <= 20) {
                if (tp <= 20) v0 = wl[ch * 441 + m * 21 + tp];
                int tq = tp + 16;
                if (tq <= 20) v1 = wl[ch * 441 + m * 21 + tq];
            } else if (m <= 25 && tp >= 8 && tp <= 12) {
                v0 = wsm[ch * 25 + (m - 21) * 5 + (tp - 8)];
            }
            A0[e] = (_Float16)v0;
            A1[e] = (_Float16)v1;
        }
    }
    __syncthreads();

    float ring0[21], ring1[21];
    #pragma unroll
    for (int s = 0; s < 21; ++s) { ring0[s] = 0.f; ring1[s] = 0.f; }
    f32x16 CZ;
    #pragma unroll
    for (int s = 0; s < 16; ++s) CZ[s] = 0.f;

    float lsum = 0.f, lss = 0.f;
    float* top = tmp + (size_t)plane * NPIX;
    const unsigned int* base = tile + (n + 4 * h);

    // prologue: r = 10..19, mask contributions with q > r (would hit y < 0)
    #pragma unroll
    for (int rr = 0; rr < 10; ++rr) {
        STEP(10 + rr, 10 + rr, 10 + rr);
    }
    // steady state: r = 20..75 (MFMA only while r < 66); emit y = r-20 each iter
    for (int bb = 0; bb < 3; ++bb) {
        #pragma unroll
        for (int u = 0; u < 21; ++u) {
            const int r = 20 + 21 * bb + u;
            if (r > 75) continue;
            if (r < 66) {
                STEP(20 + u, 20, r);
            }
            EMIT(20 + u, r);
        }
    }

    // wave reduction (hi / n>=28 lanes contributed 0)
    #pragma unroll
    for (int off = 32; off > 0; off >>= 1) {
        lsum += __shfl_down(lsum, off);
        lss  += __shfl_down(lss, off);
    }
    if (l == 0) {
        partials[2 * plane + 0] = lsum;
        partials[2 * plane + 1] = lss;
    }
}

// -------- Kernel B: per-sample mean / rstd --------
__global__ void stats_kernel(const float* __restrict__ partials, float* __restrict__ stats) {
    const int n = blockIdx.x;
    const int t = threadIdx.x;   // 64 threads
    float s = 0.f, ss = 0.f;
    for (int c = t; c < DIM; c += 64) {
        s  += partials[2 * (n * DIM + c) + 0];
        ss += partials[2 * (n * DIM + c) + 1];
    }
    #pragma unroll
    for (int off = 32; off > 0; off >>= 1) {
        s  += __shfl_down(s, off);
        ss += __shfl_down(ss, off);
    }
    if (t == 0) {
        const float inv = 1.f / 602112.f;   // DIM*HW*HW
        float mean = s * inv;
        float var = ss * inv - mean * mean;
        stats[2 * n + 0] = mean;
        stats[2 * n + 1] = rsqrtf(var + GN_EPS);
    }
}

// fast exact-GELU via Abramowitz-Stegun 7.1.26 erf (|err| <= 1.5e-7)
__device__ __forceinline__ float fast_gelu(float y) {
    float z = fabsf(y) * 0.70710678118654752f;
    float tt = __builtin_amdgcn_rcpf(1.f + 0.3275911f * z);
    float poly = tt * (0.254829592f + tt * (-0.284496736f + tt * (1.421413741f
               + tt * (-1.453152027f + tt * 1.061405429f))));
    float er = 1.f - poly * __expf(-z * z);
    er = copysignf(er, y);
    return 0.5f * y * (1.f + er);
}

// -------- Kernel C: normalize + GELU + 1x1 conv (MFMA) + bias + residual --------
__global__ __launch_bounds__(192)
void pw_kernel(const float* __restrict__ tmp, const float* __restrict__ x,
               const float* __restrict__ gamma, const float* __restrict__ beta,
               const __bf16* __restrict__ wb, const float* __restrict__ bpw,
               const float* __restrict__ stats, float* __restrict__ out) {
    __shared__ __bf16 g_lds[32 * 200];   // [px][ci], row stride 200 bf16

    const int bid = blockIdx.x;
    const int n = bid / 98;              // 98 pixel-tiles of 32 per sample
    const int pt = bid - n * 98;
    const int px0 = pt * 32;
    const int t = threadIdx.x;           // t == ci for staging

    const float mean = stats[2 * n + 0];
    const float rstd = stats[2 * n + 1];

    {
        const float a = rstd * gamma[t];
        const float b = beta[t] - mean * a;
        const float* tp = tmp + ((size_t)n * DIM + t) * NPIX + px0;
        #pragma unroll
        for (int k = 0; k < 8; ++k) {
            f32x4 v = *(const f32x4*)(tp + 4 * k);
            #pragma unroll
            for (int j = 0; j < 4; ++j) {
                float y = v[j] * a + b;
                g_lds[(4 * k + j) * 200 + t] = (__bf16)fast_gelu(y);
            }
        }
    }
    __syncthreads();

    const int w = t >> 6;                // wave id -> co block of 64
    const int l = t & 63;
    const int lane16 = l & 15, lg = l >> 4;

    f32x4 acc[2][4];
    #pragma unroll
    for (int p = 0; p < 2; ++p)
        #pragma unroll
        for (int m = 0; m < 4; ++m) { acc[p][m][0]=0.f; acc[p][m][1]=0.f; acc[p][m][2]=0.f; acc[p][m][3]=0.f; }

    const char* gbase = (const char*)g_lds;
    #pragma unroll
    for (int kk = 0; kk < 6; ++kk) {
        const int k0 = 32 * kk;
        bf16x8 bf0 = *(const bf16x8*)(gbase + lane16 * 400 + (k0 + 8 * lg) * 2);
        bf16x8 bf1 = *(const bf16x8*)(gbase + (16 + lane16) * 400 + (k0 + 8 * lg) * 2);
        #pragma unroll
        for (int m = 0; m < 4; ++m) {
            const int co = 64 * w + 16 * m + lane16;
            bf16x8 af = *(const bf16x8*)(wb + co * DIM + k0 + 8 * lg);
            acc[0][m] = __builtin_amdgcn_mfma_f32_16x16x32_bf16(af, bf0, acc[0][m], 0, 0, 0);
            acc[1][m] = __builtin_amdgcn_mfma_f32_16x16x32_bf16(af, bf1, acc[1][m], 0, 0, 0);
        }
    }

    const float* xb = x + (size_t)n * DIM * NPIX;
    float* ob = out + (size_t)n * DIM * NPIX;
    #pragma unroll
    for (int m = 0; m < 4; ++m) {
        f32x4 b4 = *(const f32x4*)(bpw + 64 * w + 16 * m + 4 * lg);
        #pragma unroll
        for (int p = 0; p < 2; ++p)
            #pragma unroll
            for (int j = 0; j < 4; ++j) {
                const int co = 64 * w + 16 * m + 4 * lg + j;
                const int idx = co * NPIX + px0 + p * 16 + lane16;
                ob[idx] = acc[p][m][j] + b4[j] + xb[idx];
            }
    }
}

extern "C" void kernel_launch(void* const* d_in, const int* in_sizes, int n_in,
                              void* d_out, int out_size, void* d_ws, size_t ws_size,
                              hipStream_t stream) {
    (void)in_sizes; (void)n_in; (void)out_size; (void)ws_size;
    const float* x     = (const float*)d_in[0];
    const float* wl    = (const float*)d_in[1];
    const float* wsm   = (const float*)d_in[2];
    const float* gamma = (const float*)d_in[3];
    const float* beta  = (const float*)d_in[4];
    const float* wpw   = (const float*)d_in[5];
    const float* bpw   = (const float*)d_in[6];
    float* out = (float*)d_out;

    char* wsb = (char*)d_ws;
    float* tmp      = (float*)wsb;
    float* partials = (float*)(wsb + WS_OFF_PARTIALS);
    float* stats    = (float*)(wsb + WS_OFF_STATS);
    __bf16* wb      = (__bf16*)(wsb + WS_OFF_WB);

    conv_w_kernel<<<144, 256, 0, stream>>>(wpw, wb);
    dwconv_kernel<<<NSAMP * DIM, 64, 0, stream>>>(x, wl, wsm, tmp, partials);
    stats_kernel<<<NSAMP, 64, 0, stream>>>(partials, stats);
    pw_kernel<<<NSAMP * 98, 192, 0, stream>>>(tmp, x, gamma, beta, wb, bpw, stats, out);
}